// Round 2
// baseline (3524.128 us; speedup 1.0000x reference)
//
#include <hip/hip_runtime.h>

#define NATOMS 50000
#define FDIM   128
#define EXDIM  64
#define NEDGE  500000
#define NPAIR  14

typedef _Float16 v8h __attribute__((ext_vector_type(8)));
typedef float    v4f __attribute__((ext_vector_type(4)));

// Pair visiting order chosen to minimize segment reloads:
// steps: k0(0,0) k1(0,1) k4(0,2) | k5(1,2) k6(1,2) k2(1,1) k3(1,1) |
//        k12(3,1) k11(3,0) k10(3,3) k13(3,2) | k7(2,2) k8(2,2) k9(2,2)
// g loads: 4 (one per i), h loads: 7, ex: 1.
__constant__ int cK[14]  = {0,1,4,5,6,2,3,12,11,10,13,7,8,9};
__constant__ int cI[14]  = {0,0,0,1,1,1,1,3,3,3,3,2,2,2};
__constant__ int cJ[14]  = {0,1,2,2,2,1,1,1,0,3,2,2,2,2};
__constant__ int cLG[14] = {1,0,0,1,0,0,0,1,0,0,0,1,0,0};
__constant__ int cLH[14] = {1,1,1,0,0,1,0,0,1,1,1,0,0,0};

// W1 (14,320,256) fp32 -> W1T fp16 in MFMA-B-fragment tile order:
// W1T[k14][nt(16)][kc(10)][quad(4)][col(16)][j(8)]
//   element = W1[k14][kc*32+quad*8+j][nt*16+col]
__global__ __launch_bounds__(256) void prep_w1(const float* __restrict__ W1,
                                               _Float16* __restrict__ W1T) {
    int tid = blockIdx.x * 256 + threadIdx.x;
    if (tid >= 14*320*256) return;
    int n   = tid & 255;
    int t   = tid >> 8;
    int kk  = t % 320;
    int k14 = t / 320;
    float v = W1[tid];
    int dst = ((((k14*16 + (n>>4))*10 + (kk>>5))*4 + ((kk>>3)&3))*16 + (n&15))*8 + (kk&7);
    W1T[dst] = (_Float16)v;
}

__global__ __launch_bounds__(256, 4) void hopping_main(
    const float* __restrict__ sfeat, const float* __restrict__ pfeat,
    const float* __restrict__ dfeat, const float* __restrict__ Sfeat,
    const int*  __restrict__ hop,   const float* __restrict__ darr,
    const float* __restrict__ exd,  const float* __restrict__ b1,
    const float* __restrict__ W2,   const float* __restrict__ b2,
    const _Float16* __restrict__ W1T, float* __restrict__ out)
{
    // MFMA-fragment-native LDS layout: seg[chunk][row64][j8], chunk = kc*4+quad.
    // A-frag ds_read_b128 and gather ds_write_b128 are both lane-contiguous
    // (16 B * 64 lanes = 1 KiB) -> zero bank conflicts. Total LDS = 40960 B
    // exactly -> 4 blocks/CU.
    __shared__ _Float16 gseg[16*64*8];   // 16 KB
    __shared__ _Float16 hseg[16*64*8];   // 16 KB
    __shared__ _Float16 exseg[8*64*8];   //  8 KB

    const int tid  = threadIdx.x;
    const int lane = tid & 63;
    const int w    = tid >> 6;
    const int col  = lane & 15;
    const int quad = lane >> 4;
    const long e0  = (long)blockIdx.x * 64;

    // per-thread row metadata (row = lane; all 4 waves gather all 64 rows)
    long eg = e0 + lane; if (eg >= NEDGE) eg = NEDGE - 1;
    const int   rl1 = hop[2*eg];
    const int   rl2 = hop[2*eg + 1];
    float dv = darr[eg];
    const float rinv = 1.0f / (dv * dv);

    // ex_d gather -> exseg (fragment order), once. No barrier here; step 0's
    // post-gather barrier covers it.
    {
        const float4* esrc = (const float4*)exd + (size_t)eg * 16;
        #pragma unroll
        for (int r = 0; r < 2; ++r) {
            int c = w*2 + r;                 // chunk 0..7
            float4 v0 = esrc[c*2];
            float4 v1 = esrc[c*2 + 1];
            v8h hv;
            hv[0]=(_Float16)v0.x; hv[1]=(_Float16)v0.y;
            hv[2]=(_Float16)v0.z; hv[3]=(_Float16)v0.w;
            hv[4]=(_Float16)v1.x; hv[5]=(_Float16)v1.y;
            hv[6]=(_Float16)v1.z; hv[7]=(_Float16)v1.w;
            *(v8h*)&exseg[(c*64 + lane)*8] = hv;
        }
    }

    #pragma unroll 1
    for (int step = 0; step < 14; ++step) {
        const int k14 = cK[step];

        if (cLG[step] | cLH[step]) {
            __syncthreads();   // all waves done reading old segments
            if (cLG[step]) {
                int i = cI[step];
                const float* tab = (i==0)?sfeat:(i==1)?pfeat:(i==2)?dfeat:Sfeat;
                const float4* src = (const float4*)tab + (size_t)rl1 * 32;
                #pragma unroll
                for (int r = 0; r < 4; ++r) {
                    int c = w*4 + r;         // chunk 0..15
                    float4 v0 = src[c*2];
                    float4 v1 = src[c*2 + 1];
                    v8h hv;
                    hv[0]=(_Float16)(v0.x*rinv); hv[1]=(_Float16)(v0.y*rinv);
                    hv[2]=(_Float16)(v0.z*rinv); hv[3]=(_Float16)(v0.w*rinv);
                    hv[4]=(_Float16)(v1.x*rinv); hv[5]=(_Float16)(v1.y*rinv);
                    hv[6]=(_Float16)(v1.z*rinv); hv[7]=(_Float16)(v1.w*rinv);
                    *(v8h*)&gseg[(c*64 + lane)*8] = hv;
                }
            }
            if (cLH[step]) {
                int j = cJ[step];
                const float* tab = (j==0)?sfeat:(j==1)?pfeat:(j==2)?dfeat:Sfeat;
                const float4* src = (const float4*)tab + (size_t)rl2 * 32;
                #pragma unroll
                for (int r = 0; r < 4; ++r) {
                    int c = w*4 + r;
                    float4 v0 = src[c*2];
                    float4 v1 = src[c*2 + 1];
                    v8h hv;
                    hv[0]=(_Float16)(v0.x*rinv); hv[1]=(_Float16)(v0.y*rinv);
                    hv[2]=(_Float16)(v0.z*rinv); hv[3]=(_Float16)(v0.w*rinv);
                    hv[4]=(_Float16)(v1.x*rinv); hv[5]=(_Float16)(v1.y*rinv);
                    hv[6]=(_Float16)(v1.z*rinv); hv[7]=(_Float16)(v1.w*rinv);
                    *(v8h*)&hseg[(c*64 + lane)*8] = hv;
                }
            }
            __syncthreads();
        }

        // ---- GEMM: H(64x256) = X(64x320) @ W1[k14](320x256), fp32 acc ----
        v4f acc[4][4];
        #pragma unroll
        for (int a = 0; a < 4; ++a)
            #pragma unroll
            for (int b = 0; b < 4; ++b)
                acc[a][b] = (v4f){0.f, 0.f, 0.f, 0.f};

        const _Float16* __restrict__ wb = W1T + (size_t)k14 * 81920;

        #pragma unroll
        for (int kc = 0; kc < 10; ++kc) {
            const _Float16* sb; int cbase;
            if (kc < 4)      { sb = gseg;  cbase = kc*4; }
            else if (kc < 8) { sb = hseg;  cbase = (kc-4)*4; }
            else             { sb = exseg; cbase = (kc-8)*4; }

            v8h af[4];
            #pragma unroll
            for (int mt = 0; mt < 4; ++mt)
                af[mt] = *(const v8h*)&sb[((cbase + quad)*64 + mt*16 + col)*8];

            v8h bf[4];
            #pragma unroll
            for (int nt = 0; nt < 4; ++nt)
                bf[nt] = *(const v8h*)&wb[(((size_t)(w*4 + nt)*10 + kc)*64 + lane)*8];

            #pragma unroll
            for (int mt = 0; mt < 4; ++mt)
                #pragma unroll
                for (int nt = 0; nt < 4; ++nt)
                    acc[mt][nt] = __builtin_amdgcn_mfma_f32_16x16x32_f16(
                        af[mt], bf[nt], acc[mt][nt], 0, 0, 0);
        }

        // ---- epilogue: bias + leaky-relu + dot W2, width-16 shuffle reduce,
        //      then one atomicAdd per (row, wave). No barriers. ----
        float p[4][4] = {};
        #pragma unroll
        for (int nt = 0; nt < 4; ++nt) {
            int n = (w*4 + nt)*16 + col;
            float b1v = b1[k14*256 + n];
            float w2v = W2[k14*256 + n];
            #pragma unroll
            for (int mt = 0; mt < 4; ++mt)
                #pragma unroll
                for (int r = 0; r < 4; ++r) {
                    float hv = acc[mt][nt][r] + b1v;
                    hv = (hv > 0.f) ? hv : 0.01f * hv;
                    p[mt][r] += hv * w2v;
                }
        }
        float b2v = (w == 0) ? b2[k14] : 0.0f;
        #pragma unroll
        for (int mt = 0; mt < 4; ++mt)
            #pragma unroll
            for (int r = 0; r < 4; ++r) {
                float v = p[mt][r];
                v += __shfl_xor(v, 1, 16);
                v += __shfl_xor(v, 2, 16);
                v += __shfl_xor(v, 4, 16);
                v += __shfl_xor(v, 8, 16);
                if (col == 0) {
                    long e = e0 + mt*16 + quad*4 + r;
                    if (e < NEDGE)
                        atomicAdd(&out[e*14 + k14], v + b2v);
                }
            }
    }
}

extern "C" void kernel_launch(void* const* d_in, const int* in_sizes, int n_in,
                              void* d_out, int out_size, void* d_ws, size_t ws_size,
                              hipStream_t stream)
{
    (void)in_sizes; (void)n_in; (void)ws_size;
    const float* sfeat = (const float*)d_in[0];
    const float* pfeat = (const float*)d_in[1];
    const float* dfeat = (const float*)d_in[2];
    const float* Sfeat = (const float*)d_in[3];
    const int*   hop   = (const int*)  d_in[4];
    const float* darr  = (const float*)d_in[5];
    const float* exd   = (const float*)d_in[6];
    const float* W1    = (const float*)d_in[7];
    const float* b1    = (const float*)d_in[8];
    const float* W2    = (const float*)d_in[9];
    const float* b2    = (const float*)d_in[10];
    _Float16* W1T = (_Float16*)d_ws;   // 14*320*256*2 B = 2.29 MB

    // epilogue accumulates with atomics -> out must start at zero
    hipMemsetAsync(d_out, 0, (size_t)out_size * sizeof(float), stream);

    // d_ws is re-poisoned before every timed call -> rebuild W1T every launch.
    prep_w1<<<dim3(4480), dim3(256), 0, stream>>>(W1, W1T);

    int nblk = (NEDGE + 63) / 64;   // 7813
    hopping_main<<<dim3(nblk), dim3(256), 0, stream>>>(
        sfeat, pfeat, dfeat, Sfeat, hop, darr, exd, b1, W2, b2, W1T, (float*)d_out);
}

// Round 3
// 3245.787 us; speedup vs baseline: 1.0858x; 1.0858x over previous
//
#include <hip/hip_runtime.h>
#include <stdint.h>

#define NEDGE  500000
#define NPAIR  14

typedef _Float16 v8h __attribute__((ext_vector_type(8)));
typedef float    v4f __attribute__((ext_vector_type(4)));

// Pair visiting order chosen to minimize segment reloads (4 g-loads, 7 h-loads):
// k0(0,0) k1(0,1) k4(0,2) | k5(1,2) k6(1,2) k2(1,1) k3(1,1) |
// k12(3,1) k11(3,0) k10(3,3) k13(3,2) | k7(2,2) k8(2,2) k9(2,2)
__constant__ int cK[14]  = {0,1,4,5,6,2,3,12,11,10,13,7,8,9};
__constant__ int cI[14]  = {0,0,0,1,1,1,1,3,3,3,3,2,2,2};
__constant__ int cJ[14]  = {0,1,2,2,2,1,1,1,0,3,2,2,2,2};
__constant__ int cLG[14] = {1,0,0,1,0,0,0,1,0,0,0,1,0,0};
__constant__ int cLH[14] = {1,1,1,0,0,1,0,0,1,1,1,0,0,0};

// W1 (14,320,256) fp32 -> W1T fp16 in MFMA-B-fragment tile order:
// W1T[k14][nt(16)][kc(10)][quad(4)][col(16)][j(8)]
__global__ __launch_bounds__(256) void prep_w1(const float* __restrict__ W1,
                                               _Float16* __restrict__ W1T) {
    int tid = blockIdx.x * 256 + threadIdx.x;
    if (tid >= 14*320*256) return;
    int n   = tid & 255;
    int t   = tid >> 8;
    int kk  = t % 320;
    int k14 = t / 320;
    float v = W1[tid];
    int dst = ((((k14*16 + (n>>4))*10 + (kk>>5))*4 + ((kk>>3)&3))*16 + (n&15))*8 + (kk&7);
    W1T[dst] = (_Float16)v;
}

// 4 feature tables (50000x128 fp32 each) -> fp16, concatenated [4][50000][128].
// UNSCALED (d^2 handling moved to epilogue via leaky-relu homogeneity).
__global__ __launch_bounds__(256) void prep_tabs(const float* __restrict__ t0,
                                                 const float* __restrict__ t1,
                                                 const float* __restrict__ t2,
                                                 const float* __restrict__ t3,
                                                 _Float16* __restrict__ dst) {
    long i8 = (long)blockIdx.x * 256 + threadIdx.x;   // one thread per 8 elems
    if (i8 >= (4L*50000*128)/8) return;
    long e = i8 * 8;
    int  t = (int)(e / 6400000L);
    long loc = e - (long)t * 6400000L;
    const float* src = (t==0 ? t0 : t==1 ? t1 : t==2 ? t2 : t3) + loc;
    float4 a = ((const float4*)src)[0];
    float4 b = ((const float4*)src)[1];
    v8h h;
    h[0]=(_Float16)a.x; h[1]=(_Float16)a.y; h[2]=(_Float16)a.z; h[3]=(_Float16)a.w;
    h[4]=(_Float16)b.x; h[5]=(_Float16)b.y; h[6]=(_Float16)b.z; h[7]=(_Float16)b.w;
    *(v8h*)(dst + e) = h;
}

// scattered per-lane 16B global gather -> LDS at (wave-uniform base + lane*16)
__device__ __forceinline__ void gather16(const _Float16* g, _Float16* l) {
    __builtin_amdgcn_global_load_lds(
        (const __attribute__((address_space(1))) uint32_t*)g,
        (__attribute__((address_space(3))) uint32_t*)l, 16, 0, 0);
}

__global__ __launch_bounds__(256, 3) void hopping_main(
    const _Float16* __restrict__ tabs,  // [4][50000][128] fp16
    const int*   __restrict__ hop,  const float* __restrict__ darr,
    const float* __restrict__ exd,  const float* __restrict__ b1,
    const float* __restrict__ W2,   const float* __restrict__ b2,
    const _Float16* __restrict__ W1T, float* __restrict__ out)
{
    // fragment-native, conflict-free (verified R2): seg[chunk16][row64][j8]
    __shared__ _Float16 gseg[16*64*8];   // 16 KB
    __shared__ _Float16 hseg[16*64*8];   // 16 KB
    __shared__ float    slab[4*14*64];   // 14 KB per-wave partial outputs
    __shared__ float    outbuf[64*14];   // 3.5 KB  -> total 50.7 KB, 3 blk/CU

    const int  tid  = threadIdx.x;
    const int  lane = tid & 63;
    const int  w    = tid >> 6;
    const int  col  = lane & 15;
    const int  quad = lane >> 4;
    const long e0   = (long)blockIdx.x * 64;

    long eg = e0 + lane; if (eg >= NEDGE) eg = NEDGE - 1;
    const int   rl1 = hop[2*eg];
    const int   rl2 = hop[2*eg + 1];
    const float dv  = darr[eg];
    const float d2own   = dv * dv;
    const float rinvown = 1.0f / d2own;

    // ex fragments in registers, rows mt*16+col, scaled by that row's d^2
    v8h exf[2][4];
    #pragma unroll
    for (int mt = 0; mt < 4; ++mt) {
        int  r_  = mt*16 + col;
        float d2r = __shfl(d2own, r_);
        long  er  = e0 + r_; if (er >= NEDGE) er = NEDGE - 1;
        const float4* ep = (const float4*)(exd + er*64);
        #pragma unroll
        for (int kc2 = 0; kc2 < 2; ++kc2) {
            float4 a = ep[(kc2*4 + quad)*2];
            float4 b = ep[(kc2*4 + quad)*2 + 1];
            v8h h;
            h[0]=(_Float16)(a.x*d2r); h[1]=(_Float16)(a.y*d2r);
            h[2]=(_Float16)(a.z*d2r); h[3]=(_Float16)(a.w*d2r);
            h[4]=(_Float16)(b.x*d2r); h[5]=(_Float16)(b.y*d2r);
            h[6]=(_Float16)(b.z*d2r); h[7]=(_Float16)(b.w*d2r);
            exf[kc2][mt] = h;
        }
    }

    // d^2 per accumulator row (for the d2*b1 bias term)
    float d2reg[4][4];
    #pragma unroll
    for (int mt = 0; mt < 4; ++mt)
        #pragma unroll
        for (int r = 0; r < 4; ++r)
            d2reg[mt][r] = __shfl(d2own, mt*16 + quad*4 + r);

    #pragma unroll 1
    for (int step = 0; step < 14; ++step) {
        const int k14 = cK[step];

        if (cLG[step] | cLH[step]) {
            __syncthreads();     // all waves done reading old segments
            if (cLG[step]) {
                const _Float16* tb = tabs + (size_t)cI[step]*6400000 + (size_t)rl1*128;
                #pragma unroll
                for (int r = 0; r < 4; ++r) {
                    int c = w*4 + r;
                    gather16(tb + c*8, &gseg[c*512]);
                }
            }
            if (cLH[step]) {
                const _Float16* tb = tabs + (size_t)cJ[step]*6400000 + (size_t)rl2*128;
                #pragma unroll
                for (int r = 0; r < 4; ++r) {
                    int c = w*4 + r;
                    gather16(tb + c*8, &hseg[c*512]);
                }
            }
            __syncthreads();     // compiler drains vmcnt before barrier
        }

        // ---- GEMM: acc(64x256) += X_unscaled(64x320) @ W1[k14] ----
        v4f acc[4][4];
        #pragma unroll
        for (int a = 0; a < 4; ++a)
            #pragma unroll
            for (int b = 0; b < 4; ++b)
                acc[a][b] = (v4f){0.f, 0.f, 0.f, 0.f};

        const _Float16* __restrict__ wb = W1T + (size_t)k14 * 81920;

        #pragma unroll
        for (int kc = 0; kc < 10; ++kc) {
            v8h af[4];
            if (kc < 8) {
                const _Float16* sb = (kc < 4) ? gseg : hseg;
                int cb = (kc & 3)*4 + quad;
                #pragma unroll
                for (int mt = 0; mt < 4; ++mt)
                    af[mt] = *(const v8h*)&sb[(cb*64 + mt*16 + col)*8];
            } else {
                #pragma unroll
                for (int mt = 0; mt < 4; ++mt)
                    af[mt] = exf[kc-8][mt];
            }
            v8h bf[4];
            #pragma unroll
            for (int nt = 0; nt < 4; ++nt)
                bf[nt] = *(const v8h*)&wb[(((size_t)(w*4 + nt)*10 + kc)*64 + lane)*8];

            #pragma unroll
            for (int mt = 0; mt < 4; ++mt)
                #pragma unroll
                for (int nt = 0; nt < 4; ++nt)
                    acc[mt][nt] = __builtin_amdgcn_mfma_f32_16x16x32_f16(
                        af[mt], bf[nt], acc[mt][nt], 0, 0, 0);
        }

        // ---- epilogue: leaky(acc + d2*b1) . w2, width-16 reduce,
        //      partials to disjoint slab (NO barrier) ----
        float p[4][4] = {};
        #pragma unroll
        for (int nt = 0; nt < 4; ++nt) {
            int n = (w*4 + nt)*16 + col;
            float b1v = b1[k14*256 + n];
            float w2v = W2[k14*256 + n];
            #pragma unroll
            for (int mt = 0; mt < 4; ++mt)
                #pragma unroll
                for (int r = 0; r < 4; ++r) {
                    float hv = fmaf(d2reg[mt][r], b1v, acc[mt][nt][r]);
                    hv = (hv > 0.f) ? hv : 0.01f * hv;
                    p[mt][r] = fmaf(hv, w2v, p[mt][r]);
                }
        }
        #pragma unroll
        for (int mt = 0; mt < 4; ++mt) {
            #pragma unroll
            for (int r = 0; r < 4; ++r) {
                float v = p[mt][r];
                v += __shfl_xor(v, 1, 16);
                v += __shfl_xor(v, 2, 16);
                v += __shfl_xor(v, 4, 16);
                v += __shfl_xor(v, 8, 16);
                p[mt][r] = v;
            }
            if (col == 0) {
                v4f pv; pv[0]=p[mt][0]; pv[1]=p[mt][1]; pv[2]=p[mt][2]; pv[3]=p[mt][3];
                *(v4f*)&slab[(w*14 + k14)*64 + mt*16 + quad*4] = pv;
            }
        }
    }

    // ---- single cross-wave reduction + scale by 1/d^2 + coalesced store ----
    __syncthreads();
    #pragma unroll
    for (int it = 0; it < 4; ++it) {
        int o = it*256 + tid;           // o = k*64 + row ; row == lane
        if (o < 64*NPAIR) {
            int k = o >> 6, row = o & 63;
            float s = slab[(0*14 + k)*64 + row] + slab[(1*14 + k)*64 + row]
                    + slab[(2*14 + k)*64 + row] + slab[(3*14 + k)*64 + row];
            outbuf[row*NPAIR + k] = rinvown * s + b2[k];
        }
    }
    __syncthreads();
    for (int o = tid; o < 64*NPAIR; o += 256) {
        long g = e0*NPAIR + o;
        if (g < (long)NEDGE*NPAIR) out[g] = outbuf[o];
    }
}

extern "C" void kernel_launch(void* const* d_in, const int* in_sizes, int n_in,
                              void* d_out, int out_size, void* d_ws, size_t ws_size,
                              hipStream_t stream)
{
    (void)in_sizes; (void)n_in; (void)out_size; (void)ws_size;
    const float* sfeat = (const float*)d_in[0];
    const float* pfeat = (const float*)d_in[1];
    const float* dfeat = (const float*)d_in[2];
    const float* Sfeat = (const float*)d_in[3];
    const int*   hop   = (const int*)  d_in[4];
    const float* darr  = (const float*)d_in[5];
    const float* exd   = (const float*)d_in[6];
    const float* W1    = (const float*)d_in[7];
    const float* b1    = (const float*)d_in[8];
    const float* W2    = (const float*)d_in[9];
    const float* b2    = (const float*)d_in[10];

    _Float16* W1T  = (_Float16*)d_ws;                          // 2.29 MB
    _Float16* tabs = (_Float16*)((char*)d_ws + 4*1024*1024);   // 51.2 MB

    // d_ws re-poisoned every call -> rebuild both every launch (cheap).
    prep_w1  <<<dim3(4480),  dim3(256), 0, stream>>>(W1, W1T);
    prep_tabs<<<dim3(12500), dim3(256), 0, stream>>>(sfeat, pfeat, dfeat, Sfeat, tabs);

    int nblk = (NEDGE + 63) / 64;   // 7813
    hopping_main<<<dim3(nblk), dim3(256), 0, stream>>>(
        tabs, hop, darr, exd, b1, W2, b2, W1T, (float*)d_out);
}